// Round 13
// baseline (485.254 us; speedup 1.0000x reference)
//
#include <hip/hip_runtime.h>

#define H 10
#define T_LEN 2048
#define BATCH 8192

typedef _Float16 f16x4 __attribute__((ext_vector_type(4)));
typedef _Float16 f16x8 __attribute__((ext_vector_type(8)));
typedef float f32x4 __attribute__((ext_vector_type(4)));

__device__ __forceinline__ f32x4 mfma_k16(f16x4 a, f16x4 b, f32x4 c) {
#if __has_builtin(__builtin_amdgcn_mfma_f32_16x16x16f16)
    return __builtin_amdgcn_mfma_f32_16x16x16f16(a, b, c, 0, 0, 0);
#else
    f32x4 d;
    asm("v_mfma_f32_16x16x16_f16 %0, %1, %2, %3"
        : "=v"(d) : "v"(a), "v"(b), "v"(c));
    return d;
#endif
}
__device__ __forceinline__ f32x4 mfma_k32(f16x8 a, f16x8 b, f32x4 c) {
#if __has_builtin(__builtin_amdgcn_mfma_f32_16x16x32_f16)
    return __builtin_amdgcn_mfma_f32_16x16x32_f16(a, b, c, 0, 0, 0);
#else
    f32x4 d;
    asm("v_mfma_f32_16x16x32_f16 %0, %1, %2, %3"
        : "=v"(d) : "v"(a), "v"(b), "v"(c));
    return d;
#endif
}

// ---------------------------------------------------------------------------
// MFMA recurrence, R12 structure with the 3-deep MFMA chain collapsed to
// 2 INDEPENDENT MFMAs (R12 counters: 374 cy/step = 106 issue + 3x~90
// dependent-MFMA latency; the chain was the cost).
//
//   M1 (16x16x32): per-lane A-slot s = (s<4 ? A_hi : A_lo)[j][r*4+(s&3)],
//       B-slot s = h_hi[r*4+(s&3)]  (B-frag = {hhi,hhi} duplicated).
//       Since A and B fragments share the same k<->(r,s) mapping, the
//       contraction = sum_c (A_hi+A_lo)[j][c]*h_hi[c]  -- convention-
//       independent (no assumption on k-slot ordering).
//   M2 (16x16x16): A_hi x h_lo, zero seed, issued in parallel with M1.
//   d = M1 + M2 (one vector add).  Dropped term: A_lo*h_lo ~1e-5 compounded
//   (same scheme as R12, which passed).
// D layout (both shapes): col=lane&15, row=(lane>>4)*4+reg (m89-verified),
// so D rows per lane == B-frag owned comps: recurrence stays 100% lane-local
// (no DPP/LDS/shuffle in the 2048-step loop -- R1-R10's transport cost).
//
// One wave serves 16 batches; 512 blocks x 64 threads.
// ---------------------------------------------------------------------------
__global__ __launch_bounds__(64)
void rnn_kernel(const float* __restrict__ x,
                const float* __restrict__ A,
                const float* __restrict__ Win,
                const float* __restrict__ bmod,
                const float* __restrict__ lW,
                const float* __restrict__ lb,
                float* __restrict__ out) {
    __shared__ double S[H][H];
    __shared__ double Pm[H][H];
    __shared__ double E[H][H];
    __shared__ float hsh[16][16];     // [comp][batch] for the epilogue
    const int tid = threadIdx.x;

    // ---- expm(skew(A)) fp64: scale 2^-8, 16 Taylor terms, 8 squarings
    // (verified R8/R9/R12: bit-identical to the original standalone kernel).
    {
        const int e0 = tid, e1 = tid + 64;
        const int i0 = e0 / H, j0 = e0 % H;
        const int i1 = e1 / H, j1 = e1 % H;
        const bool v1 = (e1 < H * H);
        double a0 = 0.0;
        if (i0 < j0) a0 = (double)A[i0 * H + j0];
        else if (i0 > j0) a0 = -(double)A[j0 * H + i0];
        a0 *= (1.0 / 256.0);
        S[i0][j0] = a0; Pm[i0][j0] = a0;
        E[i0][j0] = (i0 == j0 ? 1.0 : 0.0) + a0;
        if (v1) {
            double a1 = 0.0;
            if (i1 < j1) a1 = (double)A[i1 * H + j1];
            else if (i1 > j1) a1 = -(double)A[j1 * H + i1];
            a1 *= (1.0 / 256.0);
            S[i1][j1] = a1; Pm[i1][j1] = a1;
            E[i1][j1] = (i1 == j1 ? 1.0 : 0.0) + a1;
        }
        __syncthreads();
        for (int k = 2; k <= 16; ++k) {
            double t0 = 0.0, t1 = 0.0;
            for (int m = 0; m < H; ++m) t0 += Pm[i0][m] * S[m][j0];
            t0 *= (1.0 / (double)k);
            if (v1) {
                for (int m = 0; m < H; ++m) t1 += Pm[i1][m] * S[m][j1];
                t1 *= (1.0 / (double)k);
            }
            __syncthreads();
            Pm[i0][j0] = t0; E[i0][j0] += t0;
            if (v1) { Pm[i1][j1] = t1; E[i1][j1] += t1; }
            __syncthreads();
        }
        for (int rr = 0; rr < 8; ++rr) {
            double t0 = 0.0, t1 = 0.0;
            for (int m = 0; m < H; ++m) t0 += E[i0][m] * E[m][j0];
            if (v1) {
                for (int m = 0; m < H; ++m) t1 += E[i1][m] * E[m][j1];
            }
            __syncthreads();
            E[i0][j0] = t0;
            if (v1) E[i1][j1] = t1;
            __syncthreads();
        }
    }

    // ---- fragment setup
    const int l15  = tid & 15;        // A: row j  |  B/D: batch column
    const int rrow = tid >> 4;        // 0..3: k/row quad
    const int bb   = blockIdx.x * 16 + l15;   // this lane's batch (B/D view)

    // astk slot s = (s<4 ? A_hi : A_lo)[j=l15][rrow*4+(s&3)], A = Bmat^T.
    f16x8 astk;
    f16x4 ahi4;
#pragma unroll
    for (int s = 0; s < 4; ++s) {
        const int m = rrow * 4 + s;
        float av = (m < H && l15 < H) ? (float)E[m][l15] : 0.f;
        _Float16 ah = (_Float16)av;
        astk[s]     = ah;
        astk[s + 4] = (_Float16)(av - (float)ah);
        ahi4[s]     = ah;
    }
    // per-lane xproj/modrelu constants for OWNED comps j4 = rrow*4+s (D rows)
    float w0v[4], w1v[4], bmv[4];
#pragma unroll
    for (int s = 0; s < 4; ++s) {
        const int j4 = rrow * 4 + s;
        w0v[s] = (j4 < H) ? Win[j4 * 2]     : 0.f;
        w1v[s] = (j4 < H) ? Win[j4 * 2 + 1] : 0.f;
        bmv[s] = (j4 < H) ? bmod[j4]        : 0.f;
    }

    f16x4 hhi = {};   // h = 0
    f16x4 hlo = {};
    f32x4 hf  = {};   // f32 copy of owned h comps (for epilogue)
    const f32x4 zero4 = {};

    const float4* __restrict__ xp4 = (const float4*)(x + (size_t)bb * (T_LEN * 2));
    float4 cur[4], nxt[4];
#pragma unroll
    for (int i = 0; i < 4; ++i) cur[i] = xp4[i];

    for (int t0 = 0; t0 < T_LEN; t0 += 8) {
        if (t0 + 8 < T_LEN) {
            const int base = (t0 + 8) >> 1;
#pragma unroll
            for (int i = 0; i < 4; ++i) nxt[i] = xp4[base + i];
        }
#pragma unroll
        for (int u = 0; u < 8; ++u) {
            const int ii = u >> 1;
            const float x0 = (u & 1) ? cur[ii].z : cur[ii].x;
            const float x1 = (u & 1) ? cur[ii].w : cur[ii].y;

            // C seed = xproj for owned comps (C layout == D layout)
            f32x4 c;
#pragma unroll
            for (int s = 0; s < 4; ++s)
                c[s] = fmaf(x1, w1v[s], x0 * w0v[s]);

            // Two INDEPENDENT MFMAs, merged by one add:
            //   d1 = (A_hi+A_lo)·h_hi + xproj   (K=32, B = {hhi,hhi})
            //   d2 = A_hi·h_lo                   (K=16)
            const f16x8 bdup = __builtin_shufflevector(hhi, hhi,
                                                       0, 1, 2, 3, 0, 1, 2, 3);
            f32x4 d1 = mfma_k32(astk, bdup, c);
            f32x4 d2 = mfma_k16(ahi4, hlo, zero4);
            f32x4 d  = d1 + d2;

            // modrelu + hi/lo split (all lane-local)
#pragma unroll
            for (int s = 0; s < 4; ++s) {
                const float sv = d[s];
                const float r  = fmaxf(fabsf(sv) + bmv[s], 0.f);
                const float h  = __builtin_copysignf(r, sv);
                hf[s] = h;
                const _Float16 hh = (_Float16)h;
                hhi[s] = hh;
                hlo[s] = (_Float16)(h - (float)hh);
            }
        }
#pragma unroll
        for (int i = 0; i < 4; ++i) cur[i] = nxt[i];
    }

    // ---- epilogue: gather h via LDS, out[b][comp] = lb + h·lW[comp][:]
    __syncthreads();   // expm LDS reuse barrier (E no longer needed)
#pragma unroll
    for (int s = 0; s < 4; ++s) hsh[rrow * 4 + s][l15] = hf[s];
    __syncthreads();
    for (int i = tid; i < 16 * H; i += 64) {
        const int b = i / H, comp = i - b * H;
        float acc = lb[comp];
#pragma unroll
        for (int m = 0; m < H; ++m)
            acc = fmaf(hsh[m][b], lW[comp * H + m], acc);
        out[(size_t)(blockIdx.x * 16 + b) * H + comp] = acc;
    }
}

extern "C" void kernel_launch(void* const* d_in, const int* in_sizes, int n_in,
                              void* d_out, int out_size, void* d_ws, size_t ws_size,
                              hipStream_t stream) {
    const float* inputs = (const float*)d_in[0];  // [8192, 2048, 2]
    const float* A      = (const float*)d_in[1];  // [10, 10]
    const float* W_in   = (const float*)d_in[2];  // [10, 2]
    const float* b_mod  = (const float*)d_in[3];  // [10]
    const float* lin_W  = (const float*)d_in[4];  // [10, 10]
    const float* lin_b  = (const float*)d_in[5];  // [10]
    float* out = (float*)d_out;                   // [8192, 10]
    (void)d_ws; (void)ws_size;

    rnn_kernel<<<BATCH / 16, 64, 0, stream>>>(inputs, A, W_in, b_mod,
                                              lin_W, lin_b, out);
}

// Round 14
// 338.479 us; speedup vs baseline: 1.4336x; 1.4336x over previous
//
#include <hip/hip_runtime.h>

#define H 10
#define T_LEN 2048
#define BATCH 8192

typedef float v2f __attribute__((ext_vector_type(2)));
__device__ __forceinline__ v2f vdup(float s) { v2f r; r.x = s; r.y = s; return r; }
__device__ __forceinline__ v2f vfma2(v2f a, v2f b, v2f c) {
    return __builtin_elementwise_fma(a, b, c);
}
// row_ror:(2K) within 16-lane rows: rotates q by K preserving parity (HW-verified R1/R3/R9).
#define ROR2K(x, K) __int_as_float(__builtin_amdgcn_update_dpp(                  \
    0, __float_as_int(x), 0x120 + 2 * (K), 0xF, 0xF, true))

#define STR2(x) #x
#define XP(A, B) "v[" STR2(A) ":" STR2(B) "]"
#define MRD(D, S, N) "v_mov_b32_dpp " D ", " S " row_ror:" STR2(N)              \
                     " row_mask:0xf bank_mask:0xf\n\t"
#define SW " op_sel:[1,0,0] op_sel_hi:[0,1,1]\n\t"   // src0 halves swapped (HW-verified R3/R9)

// One recurrence step, R9 skeleton with the depth-10 accP chain split into
// FIVE short chains (X=2, P/Q/R/S=4 each) + 3-add tree + X fold.
// R9 counters: 238 cy/step = 179 issue + 59 stall at 1 wave/SIMD; scheduling
// sim attributes ~35 cy to accP's chain latency poking past the issue window.
// Cost: +3 pk_add (+12 cy issue) for ~35 cy latency removal.
// All rotations via DPP into 14 DISTINCT regs (v50-53, v30-39): no WAR.
// DPP-source hazard: first MRD is 3rd instr after prior step's v_bfi (>=2 ok).
#define STEP(A, B)                                                              \
 "v_pk_mul_f32 v[58:59], " XP(A,B) ", %[w0] op_sel:[0,0] op_sel_hi:[0,1]\n\t"   \
 "v_pk_fma_f32 v[58:59], " XP(A,B) ", %[w1], v[58:59] op_sel:[1,0,0] op_sel_hi:[1,1,1]\n\t" \
 MRD("v50","v48",2)  MRD("v51","v49",2)                                         \
 MRD("v52","v48",4)  MRD("v53","v49",4)                                         \
 "v_pk_mul_f32 v[54:55], v[48:49], %[bn0]\n\t"                                  \
 "v_pk_fma_f32 v[54:55], v[48:49], %[bs0], v[54:55]" SW                         \
 "v_pk_fma_f32 v[54:55], v[50:51], %[bn1], v[54:55]\n\t"                        \
 "v_pk_fma_f32 v[54:55], v[50:51], %[bs1], v[54:55]" SW                         \
 MRD("v30","v48",6)  MRD("v31","v49",6)                                         \
 MRD("v32","v48",8)  MRD("v33","v49",8)                                         \
 "v_pk_mul_f32 v[56:57], v[52:53], %[bn2]\n\t"                                  \
 "v_pk_fma_f32 v[56:57], v[52:53], %[bs2], v[56:57]" SW                         \
 "v_pk_fma_f32 v[56:57], v[30:31], %[bn3], v[56:57]\n\t"                        \
 "v_pk_fma_f32 v[56:57], v[30:31], %[bs3], v[56:57]" SW                         \
 MRD("v34","v48",10) MRD("v35","v49",10)                                        \
 MRD("v36","v48",12) MRD("v37","v49",12)                                        \
 "v_pk_mul_f32 v[26:27], v[32:33], %[bn4]\n\t"                                  \
 "v_pk_fma_f32 v[26:27], v[32:33], %[bs4], v[26:27]" SW                         \
 "v_pk_fma_f32 v[26:27], v[34:35], %[bn5], v[26:27]\n\t"                        \
 "v_pk_fma_f32 v[26:27], v[34:35], %[bs5], v[26:27]" SW                         \
 MRD("v38","v48",14) MRD("v39","v49",14)                                        \
 "v_pk_mul_f32 v[28:29], v[36:37], %[bn6]\n\t"                                  \
 "v_pk_fma_f32 v[28:29], v[36:37], %[bs6], v[28:29]" SW                         \
 "v_pk_fma_f32 v[28:29], v[38:39], %[bn7], v[28:29]\n\t"                        \
 "v_pk_fma_f32 v[28:29], v[38:39], %[bs7], v[28:29]" SW                         \
 "v_pk_add_f32 v[54:55], v[54:55], v[56:57]\n\t"                                \
 "v_pk_add_f32 v[26:27], v[26:27], v[28:29]\n\t"                                \
 "v_pk_add_f32 v[54:55], v[54:55], v[26:27]\n\t"                                \
 "v_pk_add_f32 v[54:55], v[54:55], v[58:59]\n\t"                                \
 "v_add_f32 v58, abs(v54), %[bm0]\n\t"                                          \
 "v_add_f32 v59, abs(v55), %[bm1]\n\t"                                          \
 "v_max_f32 v58, 0, v58\n\t"                                                    \
 "v_max_f32 v59, 0, v59\n\t"                                                    \
 "v_bfi_b32 v48, %[mk], v58, v54\n\t"                                           \
 "v_bfi_b32 v49, %[mk], v59, v55\n\t"

// Proven R6 sub-iter control: 4 dwordx4 issued 3 sub-iters ahead, vmcnt(12).
#define SUBCTL(TAG, LD0, LD1, LD2, LD3)                             \
    "s_cmp_lt_u32 %[it], 253\n\t"                                   \
    "s_cbranch_scc0 Lsk" TAG "_%=\n\t"                              \
    "global_load_dwordx4 " LD0 ", v[60:61], off\n\t"                \
    "global_load_dwordx4 " LD1 ", v[60:61], off offset:16\n\t"      \
    "global_load_dwordx4 " LD2 ", v[60:61], off offset:32\n\t"      \
    "global_load_dwordx4 " LD3 ", v[60:61], off offset:48\n\t"      \
    "v_add_co_u32 v60, vcc, 64, v60\n\t"                            \
    "v_addc_co_u32 v61, vcc, 0, v61, vcc\n\t"                       \
    "s_waitcnt vmcnt(12)\n\t"                                       \
    "s_branch Ldn" TAG "_%=\n\t"                                    \
    "Lsk" TAG "_%=:\n\t"                                            \
    "s_waitcnt vmcnt(0)\n\t"                                        \
    "Ldn" TAG "_%=:\n\t"                                            \
    "s_add_i32 %[it], %[it], 1\n\t"

// ---------------------------------------------------------------------------
// Single fused kernel: per-block fp64 expm (verified R8/R9, bit-identical B),
// then the hand-asm packed recurrence. 8 lanes/batch (R1/R3/R9 layout), 8
// batches/wave, 1024 waves = 1/SIMD.
// ---------------------------------------------------------------------------
__global__ __launch_bounds__(64, 1)
void rnn_kernel(const float* __restrict__ x,
                const float* __restrict__ A,
                const float* __restrict__ Win,
                const float* __restrict__ bmod,
                const float* __restrict__ lW,
                const float* __restrict__ lb,
                float* __restrict__ out) {
    __shared__ double S[H][H];
    __shared__ double Pm[H][H];
    __shared__ double E[H][H];
    const int tid = threadIdx.x;

    // ---- expm(skew(A)) fp64: scale 2^-8, 16 Taylor terms, 8 squarings.
    {
        const int e0 = tid, e1 = tid + 64;
        const int i0 = e0 / H, j0 = e0 % H;
        const int i1 = e1 / H, j1 = e1 % H;
        const bool v1 = (e1 < H * H);
        double a0 = 0.0;
        if (i0 < j0) a0 = (double)A[i0 * H + j0];
        else if (i0 > j0) a0 = -(double)A[j0 * H + i0];
        a0 *= (1.0 / 256.0);
        S[i0][j0] = a0; Pm[i0][j0] = a0;
        E[i0][j0] = (i0 == j0 ? 1.0 : 0.0) + a0;
        if (v1) {
            double a1 = 0.0;
            if (i1 < j1) a1 = (double)A[i1 * H + j1];
            else if (i1 > j1) a1 = -(double)A[j1 * H + i1];
            a1 *= (1.0 / 256.0);
            S[i1][j1] = a1; Pm[i1][j1] = a1;
            E[i1][j1] = (i1 == j1 ? 1.0 : 0.0) + a1;
        }
        __syncthreads();
        for (int k = 2; k <= 16; ++k) {
            double t0 = 0.0, t1 = 0.0;
            for (int m = 0; m < H; ++m) t0 += Pm[i0][m] * S[m][j0];
            t0 *= (1.0 / (double)k);
            if (v1) {
                for (int m = 0; m < H; ++m) t1 += Pm[i1][m] * S[m][j1];
                t1 *= (1.0 / (double)k);
            }
            __syncthreads();
            Pm[i0][j0] = t0; E[i0][j0] += t0;
            if (v1) { Pm[i1][j1] = t1; E[i1][j1] += t1; }
            __syncthreads();
        }
        for (int rr = 0; rr < 8; ++rr) {
            double t0 = 0.0, t1 = 0.0;
            for (int m = 0; m < H; ++m) t0 += E[i0][m] * E[m][j0];
            if (v1) {
                for (int m = 0; m < H; ++m) t1 += E[i1][m] * E[m][j1];
            }
            __syncthreads();
            E[i0][j0] = t0;
            if (v1) E[i1][j1] = t1;
            __syncthreads();
        }
    }

    // ---- packed layout setup (R3/R9-verified mapping)
    const int l16 = tid & 15;
    const int row = tid >> 4;            // 0..3
    const int par = l16 & 1;             // batch parity in the row
    const int q   = l16 >> 1;            // 0..7 comb position
    const int bb  = blockIdx.x * 8 + row * 2 + par;   // 8192 = 1024*8 exact
    const int o0  = 2 * q, o1 = o0 + 1;

    v2f Bn[8], Bs[8];
#pragma unroll
    for (int k = 0; k < 8; ++k) {
        const int m = (q - k) & 7;
        const int j0 = 2 * m, j1 = j0 + 1;
        v2f bn = vdup(0.f), bs = vdup(0.f);
        if (o0 < H) {
            if (j0 < H) bn.x = (float)E[j0][o0];
            if (j1 < H) bs.x = (float)E[j1][o0];
        }
        if (o1 < H) {
            if (j1 < H) bn.y = (float)E[j1][o1];
            if (j0 < H) bs.y = (float)E[j0][o1];
        }
        Bn[k] = bn; Bs[k] = bs;
    }
    v2f w0v = vdup(0.f), w1v = vdup(0.f);
    float bm0 = 0.f, bm1 = 0.f;
    if (o0 < H) { w0v.x = Win[o0 * 2]; w1v.x = Win[o0 * 2 + 1]; bm0 = bmod[o0]; }
    if (o1 < H) { w0v.y = Win[o1 * 2]; w1v.y = Win[o1 * 2 + 1]; bm1 = bmod[o1]; }

    float hx, hy;
    int it = 0;
    const uint64_t addr = (uint64_t)(x + (size_t)bb * (T_LEN * 2));
    const unsigned alo = (unsigned)addr, ahi = (unsigned)(addr >> 32);

    asm volatile(
        "v_mov_b32 v48, 0\n\t"
        "v_mov_b32 v49, 0\n\t"
        "v_mov_b32 v60, %[alo]\n\t"
        "v_mov_b32 v61, %[ahi]\n\t"
        "global_load_dwordx4 v[64:67],   v[60:61], off\n\t"
        "global_load_dwordx4 v[68:71],   v[60:61], off offset:16\n\t"
        "global_load_dwordx4 v[72:75],   v[60:61], off offset:32\n\t"
        "global_load_dwordx4 v[76:79],   v[60:61], off offset:48\n\t"
        "global_load_dwordx4 v[80:83],   v[60:61], off offset:64\n\t"
        "global_load_dwordx4 v[84:87],   v[60:61], off offset:80\n\t"
        "global_load_dwordx4 v[88:91],   v[60:61], off offset:96\n\t"
        "global_load_dwordx4 v[92:95],   v[60:61], off offset:112\n\t"
        "global_load_dwordx4 v[96:99],   v[60:61], off offset:128\n\t"
        "global_load_dwordx4 v[100:103], v[60:61], off offset:144\n\t"
        "global_load_dwordx4 v[104:107], v[60:61], off offset:160\n\t"
        "global_load_dwordx4 v[108:111], v[60:61], off offset:176\n\t"
        "v_add_co_u32 v60, vcc, 0xc0, v60\n\t"
        "v_addc_co_u32 v61, vcc, 0, v61, vcc\n\t"
        "Lmain_%=:\n\t"
        SUBCTL("0", "v[112:115]", "v[116:119]", "v[120:123]", "v[124:127]")
        STEP(64, 65)  STEP(66, 67)  STEP(68, 69)  STEP(70, 71)
        STEP(72, 73)  STEP(74, 75)  STEP(76, 77)  STEP(78, 79)
        SUBCTL("1", "v[64:67]", "v[68:71]", "v[72:75]", "v[76:79]")
        STEP(80, 81)  STEP(82, 83)  STEP(84, 85)  STEP(86, 87)
        STEP(88, 89)  STEP(90, 91)  STEP(92, 93)  STEP(94, 95)
        SUBCTL("2", "v[80:83]", "v[84:87]", "v[88:91]", "v[92:95]")
        STEP(96, 97)   STEP(98, 99)   STEP(100, 101) STEP(102, 103)
        STEP(104, 105) STEP(106, 107) STEP(108, 109) STEP(110, 111)
        SUBCTL("3", "v[96:99]", "v[100:103]", "v[104:107]", "v[108:111]")
        STEP(112, 113) STEP(114, 115) STEP(116, 117) STEP(118, 119)
        STEP(120, 121) STEP(122, 123) STEP(124, 125) STEP(126, 127)
        "s_cmp_lg_u32 %[it], 256\n\t"
        "s_cbranch_scc1 Lmain_%=\n\t"
        "v_mov_b32 %[hx], v48\n\t"
        "v_mov_b32 %[hy], v49\n\t"
        : [hx] "=&v"(hx), [hy] "=&v"(hy), [it] "+s"(it)
        : [alo] "v"(alo), [ahi] "v"(ahi),
          [w0] "v"(w0v), [w1] "v"(w1v), [bm0] "v"(bm0), [bm1] "v"(bm1),
          [mk] "s"(0x7fffffffu),
          [bn0] "v"(Bn[0]), [bn1] "v"(Bn[1]), [bn2] "v"(Bn[2]), [bn3] "v"(Bn[3]),
          [bn4] "v"(Bn[4]), [bn5] "v"(Bn[5]), [bn6] "v"(Bn[6]), [bn7] "v"(Bn[7]),
          [bs0] "v"(Bs[0]), [bs1] "v"(Bs[1]), [bs2] "v"(Bs[2]), [bs3] "v"(Bs[3]),
          [bs4] "v"(Bs[4]), [bs5] "v"(Bs[5]), [bs6] "v"(Bs[6]), [bs7] "v"(Bs[7])
        : "memory", "vcc", "scc",
          "v26", "v27", "v28", "v29", "v30", "v31", "v32", "v33", "v34", "v35",
          "v36", "v37", "v38", "v39",
          "v48", "v49", "v50", "v51", "v52", "v53", "v54", "v55", "v56", "v57",
          "v58", "v59", "v60", "v61",
          "v64", "v65", "v66", "v67", "v68", "v69", "v70", "v71",
          "v72", "v73", "v74", "v75", "v76", "v77", "v78", "v79",
          "v80", "v81", "v82", "v83", "v84", "v85", "v86", "v87",
          "v88", "v89", "v90", "v91", "v92", "v93", "v94", "v95",
          "v96", "v97", "v98", "v99", "v100", "v101", "v102", "v103",
          "v104", "v105", "v106", "v107", "v108", "v109", "v110", "v111",
          "v112", "v113", "v114", "v115", "v116", "v117", "v118", "v119",
          "v120", "v121", "v122", "v123", "v124", "v125", "v126", "v127");

    // epilogue (cold, R3/R9-verified): out[bb][o] = lb[o] + sum_j h_j*lW[o][j]
    v2f L0[8], L1[8];
#pragma unroll
    for (int k = 0; k < 8; ++k) {
        const int m = (q - k) & 7;
        const int j0 = 2 * m, j1 = j0 + 1;
        v2f a0 = vdup(0.f), a1 = vdup(0.f);
        if (o0 < H) {
            if (j0 < H) a0.x = lW[o0 * H + j0];
            if (j1 < H) a1.x = lW[o0 * H + j1];
        }
        if (o1 < H) {
            if (j0 < H) a0.y = lW[o1 * H + j0];
            if (j1 < H) a1.y = lW[o1 * H + j1];
        }
        L0[k] = a0; L1[k] = a1;
    }
    v2f accO = vdup(0.f);
    if (o0 < H) accO.x = lb[o0];
    if (o1 < H) accO.y = lb[o1];
    accO = vfma2(vdup(hx), L0[0], accO);
    accO = vfma2(vdup(hy), L1[0], accO);
#define OUTK(K) { const float ex_ = ROR2K(hx, K); const float ey_ = ROR2K(hy, K); \
                  accO = vfma2(vdup(ex_), L0[K], accO);                           \
                  accO = vfma2(vdup(ey_), L1[K], accO); }
    OUTK(1) OUTK(2) OUTK(3) OUTK(4) OUTK(5) OUTK(6) OUTK(7)
#undef OUTK
    if (o0 < H) {
        float2 st; st.x = accO.x; st.y = accO.y;
        *reinterpret_cast<float2*>(out + (size_t)bb * H + o0) = st;
    }
}

extern "C" void kernel_launch(void* const* d_in, const int* in_sizes, int n_in,
                              void* d_out, int out_size, void* d_ws, size_t ws_size,
                              hipStream_t stream) {
    const float* inputs = (const float*)d_in[0];  // [8192, 2048, 2]
    const float* A      = (const float*)d_in[1];  // [10, 10]
    const float* W_in   = (const float*)d_in[2];  // [10, 2]
    const float* b_mod  = (const float*)d_in[3];  // [10]
    const float* lin_W  = (const float*)d_in[4];  // [10, 10]
    const float* lin_b  = (const float*)d_in[5];  // [10]
    float* out = (float*)d_out;                   // [8192, 10]
    (void)d_ws; (void)ws_size;

    rnn_kernel<<<BATCH / 8, 64, 0, stream>>>(inputs, A, W_in, b_mod,
                                             lin_W, lin_b, out);
}

// Round 15
// 333.441 us; speedup vs baseline: 1.4553x; 1.0151x over previous
//
#include <hip/hip_runtime.h>

#define H 10
#define T_LEN 2048
#define BATCH 8192

// row_ror:K within each 16-lane row: dst lane i reads src lane (i-K)&15.
// Direction + v_fmac DPP fusion verified on HW (R1,R3,R4,R5,R6,R7 passed).
#define MOVROR(x, K) __int_as_float(__builtin_amdgcn_mov_dpp(                    \
    __float_as_int(x), 0x120 + (K), 0xF, 0xF, true))

#define STR2(x) #x
#define VREG(n) "v" STR2(n)
#define DPP_(K) " row_ror:" STR2(K) " row_mask:0xf bank_mask:0xf\n\t"

// R6's proven fused-DPP step (measured 199.5us total structure, fully
// issue-bound at 2 waves/SIMD, zero stall) with R8's proven abs() VOP3
// modifier replacing the v_and (23.25 -> 22.25 instr/step).
// Two chains v62/v63; h DPP-read is 4 instrs after h's v_bfi write (>=2 ok).
#define STEP(X0, X1)                                                \
    "v_mul_f32 v62, " VREG(X0) ", %[w0]\n\t"                        \
    "v_fmac_f32 v62, " VREG(X1) ", %[w1]\n\t"                       \
    "v_fmac_f32 v62, %[h], %[b0]\n\t"                               \
    "v_mul_f32 v63, %[h], %[b8]" DPP_(8)                            \
    "v_fmac_f32 v62, %[h], %[b1]" DPP_(1)                           \
    "v_fmac_f32 v63, %[h], %[b9]" DPP_(9)                           \
    "v_fmac_f32 v62, %[h], %[b2]" DPP_(2)                           \
    "v_fmac_f32 v63, %[h], %[b10]" DPP_(10)                         \
    "v_fmac_f32 v62, %[h], %[b3]" DPP_(3)                           \
    "v_fmac_f32 v63, %[h], %[b11]" DPP_(11)                         \
    "v_fmac_f32 v62, %[h], %[b4]" DPP_(4)                           \
    "v_fmac_f32 v63, %[h], %[b12]" DPP_(12)                         \
    "v_fmac_f32 v62, %[h], %[b5]" DPP_(5)                           \
    "v_fmac_f32 v63, %[h], %[b13]" DPP_(13)                         \
    "v_fmac_f32 v62, %[h], %[b6]" DPP_(6)                           \
    "v_fmac_f32 v63, %[h], %[b14]" DPP_(14)                         \
    "v_fmac_f32 v62, %[h], %[b7]" DPP_(7)                           \
    "v_fmac_f32 v63, %[h], %[b15]" DPP_(15)                         \
    "v_add_f32 v62, v62, v63\n\t"                                   \
    "v_add_f32 v63, abs(v62), %[bm]\n\t"                            \
    "v_max_f32 v63, 0, v63\n\t"                                     \
    "v_bfi_b32 %[h], %[mk], v63, v62\n\t"

// Proven R6 sub-iter control: 4 dwordx4 issued 3 sub-iters ahead, vmcnt(12).
#define SUBCTL(TAG, LD0, LD1, LD2, LD3)                             \
    "s_cmp_lt_u32 %[it], 253\n\t"                                   \
    "s_cbranch_scc0 Lsk" TAG "_%=\n\t"                              \
    "global_load_dwordx4 " LD0 ", v[60:61], off\n\t"                \
    "global_load_dwordx4 " LD1 ", v[60:61], off offset:16\n\t"      \
    "global_load_dwordx4 " LD2 ", v[60:61], off offset:32\n\t"      \
    "global_load_dwordx4 " LD3 ", v[60:61], off offset:48\n\t"      \
    "v_add_co_u32 v60, vcc, 64, v60\n\t"                            \
    "v_addc_co_u32 v61, vcc, 0, v61, vcc\n\t"                       \
    "s_waitcnt vmcnt(12)\n\t"                                       \
    "s_branch Ldn" TAG "_%=\n\t"                                    \
    "Lsk" TAG "_%=:\n\t"                                            \
    "s_waitcnt vmcnt(0)\n\t"                                        \
    "Ldn" TAG "_%=:\n\t"                                            \
    "s_add_i32 %[it], %[it], 1\n\t"

// ---------------------------------------------------------------------------
// Single fused kernel = R8's frame (fused fp64 expm, verified bit-identical)
// + R6's fused-DPP hand-asm loop (fastest measured rnn: 199.5us) + abs tail.
// 16 lanes/batch (h[j] per lane, H 10->16, pads provably stay 0), 4 batches/
// wave, 2048 waves = 2/SIMD (fully issue-bound, zero stall -- R6 counters).
// 4 fixed x-buffers v64..v127 (8 steps each), depth-3 prefetch, vmcnt(12).
// ---------------------------------------------------------------------------
__global__ __launch_bounds__(64, 2)
void rnn_kernel(const float* __restrict__ x,
                const float* __restrict__ A,
                const float* __restrict__ Win,
                const float* __restrict__ bmod,
                const float* __restrict__ lW,
                const float* __restrict__ lb,
                float* __restrict__ out) {
    __shared__ double S[H][H];
    __shared__ double Pm[H][H];
    __shared__ double E[H][H];
    const int tid = threadIdx.x;

    // ---- expm(skew(A)) fp64: scale 2^-8, 16 Taylor terms, 8 squarings
    // (verified R8/R9: bit-identical to the original standalone kernel).
    {
        const int e0 = tid, e1 = tid + 64;
        const int i0 = e0 / H, j0 = e0 % H;
        const int i1 = e1 / H, j1 = e1 % H;
        const bool v1 = (e1 < H * H);
        double a0 = 0.0;
        if (i0 < j0) a0 = (double)A[i0 * H + j0];
        else if (i0 > j0) a0 = -(double)A[j0 * H + i0];
        a0 *= (1.0 / 256.0);
        S[i0][j0] = a0; Pm[i0][j0] = a0;
        E[i0][j0] = (i0 == j0 ? 1.0 : 0.0) + a0;
        if (v1) {
            double a1 = 0.0;
            if (i1 < j1) a1 = (double)A[i1 * H + j1];
            else if (i1 > j1) a1 = -(double)A[j1 * H + i1];
            a1 *= (1.0 / 256.0);
            S[i1][j1] = a1; Pm[i1][j1] = a1;
            E[i1][j1] = (i1 == j1 ? 1.0 : 0.0) + a1;
        }
        __syncthreads();
        for (int k = 2; k <= 16; ++k) {
            double t0 = 0.0, t1 = 0.0;
            for (int m = 0; m < H; ++m) t0 += Pm[i0][m] * S[m][j0];
            t0 *= (1.0 / (double)k);
            if (v1) {
                for (int m = 0; m < H; ++m) t1 += Pm[i1][m] * S[m][j1];
                t1 *= (1.0 / (double)k);
            }
            __syncthreads();
            Pm[i0][j0] = t0; E[i0][j0] += t0;
            if (v1) { Pm[i1][j1] = t1; E[i1][j1] += t1; }
            __syncthreads();
        }
        for (int rr = 0; rr < 8; ++rr) {
            double t0 = 0.0, t1 = 0.0;
            for (int m = 0; m < H; ++m) t0 += E[i0][m] * E[m][j0];
            if (v1) {
                for (int m = 0; m < H; ++m) t1 += E[i1][m] * E[m][j1];
            }
            __syncthreads();
            E[i0][j0] = t0;
            if (v1) E[i1][j1] = t1;
            __syncthreads();
        }
    }

    // ---- recurrence setup (R6/R8 16-lane layout)
    const int j    = tid & 15;           // owned h component
    const int row  = tid >> 4;           // 0..3: batch within wave
    const int bb   = blockIdx.x * 4 + row;   // 8192 = 2048*4 exact

    // Rotation k delivers h[(j-k)&15]; Bv[k] = B[(j-k)&15][j] (0 on pads).
    float Bv[16];
#pragma unroll
    for (int k = 0; k < 16; ++k) {
        const int m = (j - k) & 15;
        Bv[k] = (j < H && m < H) ? (float)E[m][j] : 0.f;
    }
    float w0j = 0.f, w1j = 0.f, bmj = 0.f;
    if (j < H) { w0j = Win[j * 2]; w1j = Win[j * 2 + 1]; bmj = bmod[j]; }

    float h = 0.f;
    int it = 0;
    const uint64_t addr = (uint64_t)(x + (size_t)bb * (T_LEN * 2));
    const unsigned alo = (unsigned)addr, ahi = (unsigned)(addr >> 32);

    asm volatile(
        // addr regs + prologue: stage bufs 0..2 (12 loads, 192 B)
        "v_mov_b32 v60, %[alo]\n\t"
        "v_mov_b32 v61, %[ahi]\n\t"
        "global_load_dwordx4 v[64:67],   v[60:61], off\n\t"
        "global_load_dwordx4 v[68:71],   v[60:61], off offset:16\n\t"
        "global_load_dwordx4 v[72:75],   v[60:61], off offset:32\n\t"
        "global_load_dwordx4 v[76:79],   v[60:61], off offset:48\n\t"
        "global_load_dwordx4 v[80:83],   v[60:61], off offset:64\n\t"
        "global_load_dwordx4 v[84:87],   v[60:61], off offset:80\n\t"
        "global_load_dwordx4 v[88:91],   v[60:61], off offset:96\n\t"
        "global_load_dwordx4 v[92:95],   v[60:61], off offset:112\n\t"
        "global_load_dwordx4 v[96:99],   v[60:61], off offset:128\n\t"
        "global_load_dwordx4 v[100:103], v[60:61], off offset:144\n\t"
        "global_load_dwordx4 v[104:107], v[60:61], off offset:160\n\t"
        "global_load_dwordx4 v[108:111], v[60:61], off offset:176\n\t"
        "v_add_co_u32 v60, vcc, 0xc0, v60\n\t"
        "v_addc_co_u32 v61, vcc, 0, v61, vcc\n\t"
        "Lmain_%=:\n\t"
        // sub0: reads buf0 (v64-79), issues buf3 (v112-127)
        SUBCTL("0", "v[112:115]", "v[116:119]", "v[120:123]", "v[124:127]")
        STEP(64, 65)  STEP(66, 67)  STEP(68, 69)  STEP(70, 71)
        STEP(72, 73)  STEP(74, 75)  STEP(76, 77)  STEP(78, 79)
        // sub1: reads buf1 (v80-95), issues buf0 (v64-79)
        SUBCTL("1", "v[64:67]", "v[68:71]", "v[72:75]", "v[76:79]")
        STEP(80, 81)  STEP(82, 83)  STEP(84, 85)  STEP(86, 87)
        STEP(88, 89)  STEP(90, 91)  STEP(92, 93)  STEP(94, 95)
        // sub2: reads buf2 (v96-111), issues buf1 (v80-95)
        SUBCTL("2", "v[80:83]", "v[84:87]", "v[88:91]", "v[92:95]")
        STEP(96, 97)  STEP(98, 99)  STEP(100, 101) STEP(102, 103)
        STEP(104, 105) STEP(106, 107) STEP(108, 109) STEP(110, 111)
        // sub3: reads buf3 (v112-127), issues buf2 (v96-111)
        SUBCTL("3", "v[96:99]", "v[100:103]", "v[104:107]", "v[108:111]")
        STEP(112, 113) STEP(114, 115) STEP(116, 117) STEP(118, 119)
        STEP(120, 121) STEP(122, 123) STEP(124, 125) STEP(126, 127)
        "s_cmp_lg_u32 %[it], 256\n\t"
        "s_cbranch_scc1 Lmain_%=\n\t"
        : [h] "+v"(h), [it] "+s"(it)
        : [alo] "v"(alo), [ahi] "v"(ahi),
          [w0] "v"(w0j), [w1] "v"(w1j), [bm] "v"(bmj),
          [mk] "s"(0x7fffffffu),
          [b0] "v"(Bv[0]),  [b1] "v"(Bv[1]),  [b2] "v"(Bv[2]),  [b3] "v"(Bv[3]),
          [b4] "v"(Bv[4]),  [b5] "v"(Bv[5]),  [b6] "v"(Bv[6]),  [b7] "v"(Bv[7]),
          [b8] "v"(Bv[8]),  [b9] "v"(Bv[9]),  [b10] "v"(Bv[10]), [b11] "v"(Bv[11]),
          [b12] "v"(Bv[12]), [b13] "v"(Bv[13]), [b14] "v"(Bv[14]), [b15] "v"(Bv[15])
        : "memory", "vcc", "scc",
          "v60", "v61", "v62", "v63", "v64", "v65", "v66", "v67", "v68", "v69",
          "v70", "v71", "v72", "v73", "v74", "v75", "v76", "v77", "v78", "v79",
          "v80", "v81", "v82", "v83", "v84", "v85", "v86", "v87", "v88", "v89",
          "v90", "v91", "v92", "v93", "v94", "v95", "v96", "v97", "v98", "v99",
          "v100", "v101", "v102", "v103", "v104", "v105", "v106", "v107",
          "v108", "v109", "v110", "v111", "v112", "v113", "v114", "v115",
          "v116", "v117", "v118", "v119", "v120", "v121", "v122", "v123",
          "v124", "v125", "v126", "v127");

    // epilogue: out[bb][j] = lb[j] + sum_m h[m] * lW[j][m] (cold; builtin DPP)
    float Lrot[16];
#pragma unroll
    for (int k = 0; k < 16; ++k) {
        const int m = (j - k) & 15;
        Lrot[k] = (j < H && m < H) ? lW[j * H + m] : 0.f;
    }
    float acc = (j < H) ? lb[j] : 0.f;
    acc = fmaf(h, Lrot[0], acc);
#define OUTK(K) { const float e_ = MOVROR(h, K); acc = fmaf(e_, Lrot[K], acc); }
    OUTK(1)  OUTK(2)  OUTK(3)  OUTK(4)  OUTK(5)
    OUTK(6)  OUTK(7)  OUTK(8)  OUTK(9)  OUTK(10)
    OUTK(11) OUTK(12) OUTK(13) OUTK(14) OUTK(15)
#undef OUTK
    if (j < H) out[(size_t)bb * H + j] = acc;
}

extern "C" void kernel_launch(void* const* d_in, const int* in_sizes, int n_in,
                              void* d_out, int out_size, void* d_ws, size_t ws_size,
                              hipStream_t stream) {
    const float* inputs = (const float*)d_in[0];  // [8192, 2048, 2]
    const float* A      = (const float*)d_in[1];  // [10, 10]
    const float* W_in   = (const float*)d_in[2];  // [10, 2]
    const float* b_mod  = (const float*)d_in[3];  // [10]
    const float* lin_W  = (const float*)d_in[4];  // [10, 10]
    const float* lin_b  = (const float*)d_in[5];  // [10]
    float* out = (float*)d_out;                   // [8192, 10]
    (void)d_ws; (void)ws_size;

    rnn_kernel<<<BATCH / 4, 64, 0, stream>>>(inputs, A, W_in, b_mod,
                                             lin_W, lin_b, out);
}